// Round 1
// baseline (2250.923 us; speedup 1.0000x reference)
//
#include <hip/hip_runtime.h>
#include <hip/hip_bf16.h>

#define NN 50000
#define EE 800000
#define BB 512
#define DIN 128
#define HH 64
#define DOUT 32
#define BN_EPS 1e-5f

// ---------------- proj: Q = X @ W  (no bias; bias folded into stats pass) ----------------
template <int CIN>
__global__ __launch_bounds__(256) void proj_kernel(const float* __restrict__ X,
                                                   const float* __restrict__ W,  // [CIN][64]
                                                   float* __restrict__ Q)        // [N][64]
{
    __shared__ float sW[CIN * 64];
    __shared__ float sX[16 * CIN];
    const int tid = threadIdx.x;
    const int row0 = blockIdx.x * 16;

    for (int i = tid; i < CIN * 16; i += 256)            // CIN*64/4 float4s
        ((float4*)sW)[i] = ((const float4*)W)[i];
    const float* Xb = X + (size_t)row0 * CIN;
    for (int i = tid; i < 16 * CIN / 4; i += 256)
        ((float4*)sX)[i] = ((const float4*)Xb)[i];
    __syncthreads();

    const int col = tid & 63;
    const int r0  = tid >> 6;  // 0..3
    float acc[4] = {0.f, 0.f, 0.f, 0.f};
    for (int k = 0; k < CIN; k += 4) {
        const float w0 = sW[(k + 0) * 64 + col];
        const float w1 = sW[(k + 1) * 64 + col];
        const float w2 = sW[(k + 2) * 64 + col];
        const float w3 = sW[(k + 3) * 64 + col];
#pragma unroll
        for (int rr = 0; rr < 4; ++rr) {
            const float4 xv = *(const float4*)&sX[(r0 + rr * 4) * CIN + k];
            acc[rr] = fmaf(xv.x, w0, acc[rr]);
            acc[rr] = fmaf(xv.y, w1, acc[rr]);
            acc[rr] = fmaf(xv.z, w2, acc[rr]);
            acc[rr] = fmaf(xv.w, w3, acc[rr]);
        }
    }
#pragma unroll
    for (int rr = 0; rr < 4; ++rr) {
        const int row = row0 + r0 + rr * 4;
        Q[(size_t)row * 64 + col] = acc[rr];
    }
}

// ---------------- aggregate: Agg[dst] += Q[src], 64 features ----------------
__global__ __launch_bounds__(256) void agg_kernel(const float* __restrict__ Q,
                                                  const int* __restrict__ src,
                                                  const int* __restrict__ dst,
                                                  float* __restrict__ Agg)
{
    const int gid = blockIdx.x * 256 + threadIdx.x;  // E*16 threads exactly
    const int e  = gid >> 4;
    const int c4 = gid & 15;
    const int s = src[e];
    const int d = dst[e];
    const float4 v = ((const float4*)Q)[(size_t)s * 16 + c4];
    float* ap = Agg + (size_t)d * 64 + c4 * 4;
    atomicAdd(ap + 0, v.x);
    atomicAdd(ap + 1, v.y);
    atomicAdd(ap + 2, v.z);
    atomicAdd(ap + 3, v.w);
}

// ---------------- stats: Z = Q + Agg + b1 (in place over Q), column sums/sumsq ----------------
__global__ __launch_bounds__(256) void stats_kernel(float* __restrict__ Q,   // becomes Z
                                                    const float* __restrict__ Agg,
                                                    const float* __restrict__ b1,
                                                    float* __restrict__ sums,   // [64]
                                                    float* __restrict__ sumsq)  // [64]
{
    const int tid = threadIdx.x;
    const int c4 = tid & 15;
    const int rl = tid >> 4;  // 0..15
    const float4 bb = ((const float4*)b1)[c4];
    float4 s  = {0.f, 0.f, 0.f, 0.f};
    float4 ss = {0.f, 0.f, 0.f, 0.f};
    const int rowstep = 16 * gridDim.x;
    for (int r = blockIdx.x * 16 + rl; r < NN; r += rowstep) {
        const float4 q = ((const float4*)Q)[(size_t)r * 16 + c4];
        const float4 a = ((const float4*)Agg)[(size_t)r * 16 + c4];
        float4 z;
        z.x = q.x + a.x + bb.x;
        z.y = q.y + a.y + bb.y;
        z.z = q.z + a.z + bb.z;
        z.w = q.w + a.w + bb.w;
        ((float4*)Q)[(size_t)r * 16 + c4] = z;
        s.x += z.x; s.y += z.y; s.z += z.z; s.w += z.w;
        ss.x += z.x * z.x; ss.y += z.y * z.y; ss.z += z.z * z.z; ss.w += z.w * z.w;
    }
    __shared__ float red[256 * 8];
    float* rp = &red[tid * 8];
    rp[0] = s.x; rp[1] = s.y; rp[2] = s.z; rp[3] = s.w;
    rp[4] = ss.x; rp[5] = ss.y; rp[6] = ss.z; rp[7] = ss.w;
    __syncthreads();
    if (tid < 16) {
        float acc[8] = {0, 0, 0, 0, 0, 0, 0, 0};
        for (int r2 = 0; r2 < 16; ++r2) {
            const float* q2 = &red[(r2 * 16 + tid) * 8];
#pragma unroll
            for (int j = 0; j < 8; ++j) acc[j] += q2[j];
        }
#pragma unroll
        for (int j = 0; j < 4; ++j) {
            atomicAdd(&sums[tid * 4 + j], acc[j]);
            atomicAdd(&sumsq[tid * 4 + j], acc[4 + j]);
        }
    }
}

// ---------------- BN finalize: scale/shift per column ----------------
__global__ void bn_finalize(const float* __restrict__ sums, const float* __restrict__ sumsq,
                            const float* __restrict__ g, const float* __restrict__ bt,
                            float* __restrict__ scale, float* __restrict__ shift)
{
    const int c = threadIdx.x;
    const float inv_n = 1.0f / (float)NN;
    const float mean = sums[c] * inv_n;
    const float var = fmaxf(sumsq[c] * inv_n - mean * mean, 0.f);
    const float sc = g[c] * rsqrtf(var + BN_EPS);
    scale[c] = sc;
    shift[c] = bt[c] - mean * sc;
}

// ---------------- gemm2: out = relu( relu(Z*scale+shift) @ W2 + b2 ); optional fused pooling ----------------
template <bool POOL>
__global__ __launch_bounds__(256) void gemm2_kernel(const float* __restrict__ Z,
                                                    const float* __restrict__ scale,
                                                    const float* __restrict__ shift,
                                                    const float* __restrict__ W2,  // [64][64]
                                                    const float* __restrict__ b2,
                                                    const int* __restrict__ batch,
                                                    float* __restrict__ out)  // X_next [N][64] or pooled [B][64]
{
    __shared__ float sW[64 * 64];
    __shared__ float sH[16 * 64];
    const int tid = threadIdx.x;
    const int row0 = blockIdx.x * 16;

    for (int i = tid; i < 64 * 16; i += 256)
        ((float4*)sW)[i] = ((const float4*)W2)[i];
    const float4* Zb = (const float4*)(Z + (size_t)row0 * 64);
    for (int i = tid; i < 16 * 16; i += 256) {
        const float4 z = Zb[i];
        const int c4 = i & 15;
        const float4 sc = ((const float4*)scale)[c4];
        const float4 sh = ((const float4*)shift)[c4];
        float4 h;
        h.x = fmaxf(fmaf(z.x, sc.x, sh.x), 0.f);
        h.y = fmaxf(fmaf(z.y, sc.y, sh.y), 0.f);
        h.z = fmaxf(fmaf(z.z, sc.z, sh.z), 0.f);
        h.w = fmaxf(fmaf(z.w, sc.w, sh.w), 0.f);
        ((float4*)sH)[i] = h;
    }
    __syncthreads();

    const int col = tid & 63;
    const int r0  = tid >> 6;
    const float bc = b2[col];
    float acc[4] = {bc, bc, bc, bc};
    for (int k = 0; k < 64; k += 4) {
        const float w0 = sW[(k + 0) * 64 + col];
        const float w1 = sW[(k + 1) * 64 + col];
        const float w2 = sW[(k + 2) * 64 + col];
        const float w3 = sW[(k + 3) * 64 + col];
#pragma unroll
        for (int rr = 0; rr < 4; ++rr) {
            const float4 hv = *(const float4*)&sH[(r0 + rr * 4) * 64 + k];
            acc[rr] = fmaf(hv.x, w0, acc[rr]);
            acc[rr] = fmaf(hv.y, w1, acc[rr]);
            acc[rr] = fmaf(hv.z, w2, acc[rr]);
            acc[rr] = fmaf(hv.w, w3, acc[rr]);
        }
    }
#pragma unroll
    for (int rr = 0; rr < 4; ++rr) {
        const int row = row0 + r0 + rr * 4;
        const float v = fmaxf(acc[rr], 0.f);
        if (POOL) {
            atomicAdd(&out[(size_t)batch[row] * 64 + col], v);
        } else {
            out[(size_t)row * 64 + col] = v;
        }
    }
}

// ---------------- final MLP: out = relu(P @ fW1 + fb1) @ fW2 + fb2 ----------------
__global__ __launch_bounds__(256) void final_mlp(const float* __restrict__ P,   // [512][64]
                                                 const float* __restrict__ W1,  // [64][64]
                                                 const float* __restrict__ b1,
                                                 const float* __restrict__ W2,  // [64][32]
                                                 const float* __restrict__ b2,
                                                 float* __restrict__ out)       // [512][32]
{
    __shared__ float sW1[64 * 64];
    __shared__ float sW2[64 * 32];
    __shared__ float sH[4 * 64];
    const int tid = threadIdx.x;
    const int row0 = blockIdx.x * 4;

    for (int i = tid; i < 1024; i += 256) ((float4*)sW1)[i] = ((const float4*)W1)[i];
    for (int i = tid; i < 512; i += 256) ((float4*)sW2)[i] = ((const float4*)W2)[i];
    __syncthreads();

    const int col = tid & 63;
    const int r = tid >> 6;
    float acc = b1[col];
    const float* prow = P + (size_t)(row0 + r) * 64;
    for (int k = 0; k < 64; ++k) acc = fmaf(prow[k], sW1[k * 64 + col], acc);
    sH[r * 64 + col] = fmaxf(acc, 0.f);
    __syncthreads();

    if (tid < 128) {
        const int c = tid & 31;
        const int r2 = tid >> 5;
        float a2 = b2[c];
        for (int k = 0; k < 64; ++k) a2 = fmaf(sH[r2 * 64 + k], sW2[k * 32 + c], a2);
        out[(size_t)(row0 + r2) * 32 + c] = a2;
    }
}

extern "C" void kernel_launch(void* const* d_in, const int* in_sizes, int n_in,
                              void* d_out, int out_size, void* d_ws, size_t ws_size,
                              hipStream_t stream)
{
    const float* x   = (const float*)d_in[0];
    const int* ei    = (const int*)d_in[1];   // [2][E]: first E = src, next E = dst
    const int* batch = (const int*)d_in[2];
    // d_in[3] = batch_size scalar (512, hardcoded)
    const float* cW1[3] = {(const float*)d_in[4],  (const float*)d_in[10], (const float*)d_in[16]};
    const float* cb1[3] = {(const float*)d_in[5],  (const float*)d_in[11], (const float*)d_in[17]};
    const float* cg1[3] = {(const float*)d_in[6],  (const float*)d_in[12], (const float*)d_in[18]};
    const float* cbt[3] = {(const float*)d_in[7],  (const float*)d_in[13], (const float*)d_in[19]};
    const float* cW2[3] = {(const float*)d_in[8],  (const float*)d_in[14], (const float*)d_in[20]};
    const float* cb2[3] = {(const float*)d_in[9],  (const float*)d_in[15], (const float*)d_in[21]};
    const float* fW1 = (const float*)d_in[22];
    const float* fb1 = (const float*)d_in[23];
    const float* fW2 = (const float*)d_in[24];
    const float* fb2 = (const float*)d_in[25];
    float* out = (float*)d_out;

    float* bufX   = (float*)d_ws;            // N*64
    float* q      = bufX + (size_t)NN * 64;  // N*64 (becomes Z in place)
    float* agg    = q + (size_t)NN * 64;     // N*64
    float* pooled = agg + (size_t)NN * 64;   // B*64
    float* sums   = pooled + (size_t)BB * 64;  // 64 + 64 (sumsq contiguous)
    float* sumsq  = sums + 64;
    float* scale  = sumsq + 64;
    float* shift  = scale + 64;

    const int* esrc = ei;
    const int* edst = ei + EE;

    const int gemm_blocks = NN / 16;       // 3125
    const int agg_blocks  = EE * 16 / 256; // 50000

    for (int layer = 0; layer < 3; ++layer) {
        // 1) projection q = x_cur @ W1
        if (layer == 0)
            proj_kernel<DIN><<<gemm_blocks, 256, 0, stream>>>(x, cW1[0], q);
        else
            proj_kernel<HH><<<gemm_blocks, 256, 0, stream>>>(bufX, cW1[layer], q);

        // 2) aggregate in projected space
        hipMemsetAsync(agg, 0, (size_t)NN * 64 * sizeof(float), stream);
        agg_kernel<<<agg_blocks, 256, 0, stream>>>(q, esrc, edst, agg);

        // 3) z = q + agg + b1 (in place), BN column stats
        hipMemsetAsync(sums, 0, 128 * sizeof(float), stream);
        stats_kernel<<<200, 256, 0, stream>>>(q, agg, cb1[layer], sums, sumsq);

        // 4) BN scale/shift
        bn_finalize<<<1, 64, 0, stream>>>(sums, sumsq, cg1[layer], cbt[layer], scale, shift);

        // 5) second linear (+ReLU); last layer fuses graph pooling
        if (layer < 2) {
            gemm2_kernel<false><<<gemm_blocks, 256, 0, stream>>>(q, scale, shift, cW2[layer],
                                                                 cb2[layer], nullptr, bufX);
        } else {
            hipMemsetAsync(pooled, 0, (size_t)BB * 64 * sizeof(float), stream);
            gemm2_kernel<true><<<gemm_blocks, 256, 0, stream>>>(q, scale, shift, cW2[layer],
                                                                cb2[layer], batch, pooled);
        }
    }

    // final MLP on pooled graph features
    final_mlp<<<BB / 4, 256, 0, stream>>>(pooled, fW1, fb1, fW2, fb2, out);
}

// Round 2
// 408.017 us; speedup vs baseline: 5.5167x; 5.5167x over previous
//
#include <hip/hip_runtime.h>
#include <hip/hip_bf16.h>

#define NN 50000
#define EE 800000
#define BB 512
#define DIN 128
#define HH 64
#define DOUT 32
#define BN_EPS 1e-5f
#define SCAN_BLOCKS 196  // ceil(50000/256)

// ---------------- proj: Q = X @ W  (no bias; bias folded into gather) ----------------
template <int CIN>
__global__ __launch_bounds__(256) void proj_kernel(const float* __restrict__ X,
                                                   const float* __restrict__ W,  // [CIN][64]
                                                   float* __restrict__ Q)        // [N][64]
{
    __shared__ float sW[CIN * 64];
    __shared__ float sX[16 * CIN];
    const int tid = threadIdx.x;
    const int row0 = blockIdx.x * 16;

    for (int i = tid; i < CIN * 16; i += 256)
        ((float4*)sW)[i] = ((const float4*)W)[i];
    const float* Xb = X + (size_t)row0 * CIN;
    for (int i = tid; i < 16 * CIN / 4; i += 256)
        ((float4*)sX)[i] = ((const float4*)Xb)[i];
    __syncthreads();

    const int col = tid & 63;
    const int r0  = tid >> 6;  // 0..3
    float acc[4] = {0.f, 0.f, 0.f, 0.f};
    for (int k = 0; k < CIN; k += 4) {
        const float w0 = sW[(k + 0) * 64 + col];
        const float w1 = sW[(k + 1) * 64 + col];
        const float w2 = sW[(k + 2) * 64 + col];
        const float w3 = sW[(k + 3) * 64 + col];
#pragma unroll
        for (int rr = 0; rr < 4; ++rr) {
            const float4 xv = *(const float4*)&sX[(r0 + rr * 4) * CIN + k];
            acc[rr] = fmaf(xv.x, w0, acc[rr]);
            acc[rr] = fmaf(xv.y, w1, acc[rr]);
            acc[rr] = fmaf(xv.z, w2, acc[rr]);
            acc[rr] = fmaf(xv.w, w3, acc[rr]);
        }
    }
#pragma unroll
    for (int rr = 0; rr < 4; ++rr) {
        const int row = row0 + r0 + rr * 4;
        Q[(size_t)row * 64 + col] = acc[rr];
    }
}

// ---------------- CSR build: histogram -> scan -> scatter ----------------
__global__ __launch_bounds__(256) void hist_kernel(const int* __restrict__ dst,
                                                   int* __restrict__ deg)
{
    const int e = blockIdx.x * 256 + threadIdx.x;  // exactly E threads
    atomicAdd(&deg[dst[e]], 1);
}

__global__ __launch_bounds__(256) void scanA_kernel(const int* __restrict__ deg,
                                                    int* __restrict__ offs,
                                                    int* __restrict__ blockSums)
{
    __shared__ int s[256];
    const int t = threadIdx.x;
    const int i = blockIdx.x * 256 + t;
    const int v = (i < NN) ? deg[i] : 0;
    s[t] = v;
    __syncthreads();
    for (int off = 1; off < 256; off <<= 1) {
        const int a = (t >= off) ? s[t - off] : 0;
        __syncthreads();
        s[t] += a;
        __syncthreads();
    }
    if (i < NN) offs[i] = s[t] - v;  // exclusive intra-block
    if (t == 255) blockSums[blockIdx.x] = s[255];
}

__global__ __launch_bounds__(256) void scanB_kernel(const int* __restrict__ blockSums,
                                                    int* __restrict__ blockOff)
{
    __shared__ int s[256];
    const int t = threadIdx.x;
    const int v = (t < SCAN_BLOCKS) ? blockSums[t] : 0;
    s[t] = v;
    __syncthreads();
    for (int off = 1; off < 256; off <<= 1) {
        const int a = (t >= off) ? s[t - off] : 0;
        __syncthreads();
        s[t] += a;
        __syncthreads();
    }
    if (t < SCAN_BLOCKS) blockOff[t] = s[t] - v;  // exclusive
}

__global__ __launch_bounds__(256) void scanC_kernel(int* __restrict__ offs,
                                                    int* __restrict__ cursor,
                                                    const int* __restrict__ blockOff)
{
    const int i = blockIdx.x * 256 + threadIdx.x;
    if (i < NN) {
        const int o = offs[i] + blockOff[blockIdx.x];
        offs[i] = o;
        cursor[i] = o;
    }
    if (i == 0) offs[NN] = EE;
}

__global__ __launch_bounds__(256) void scatter_kernel(const int* __restrict__ src,
                                                      const int* __restrict__ dst,
                                                      int* __restrict__ cursor,
                                                      int* __restrict__ srcSorted)
{
    const int e = blockIdx.x * 256 + threadIdx.x;  // exactly E threads
    const int pos = atomicAdd(&cursor[dst[e]], 1);
    srcSorted[pos] = src[e];
}

// ---------------- gather: Z[n] = Q[n] + b1 + sum_{src in CSR[n]} Q[src] ----------------
__global__ __launch_bounds__(256) void gather_kernel(const float* __restrict__ Q,
                                                     const int* __restrict__ offs,
                                                     const int* __restrict__ srcSorted,
                                                     const float* __restrict__ b1,
                                                     float* __restrict__ Z)
{
    const int tid  = threadIdx.x;
    const int col  = tid & 63;
    const int node = blockIdx.x * 4 + (tid >> 6);  // one wave per node
    const int o0 = offs[node];
    const int o1 = offs[node + 1];
    float acc = Q[(size_t)node * 64 + col] + b1[col];
    int j = o0;
    for (; j + 4 <= o1; j += 4) {
        const int i0 = srcSorted[j + 0];
        const int i1 = srcSorted[j + 1];
        const int i2 = srcSorted[j + 2];
        const int i3 = srcSorted[j + 3];
        const float a0 = Q[(size_t)i0 * 64 + col];
        const float a1 = Q[(size_t)i1 * 64 + col];
        const float a2 = Q[(size_t)i2 * 64 + col];
        const float a3 = Q[(size_t)i3 * 64 + col];
        acc += a0; acc += a1; acc += a2; acc += a3;
    }
    for (; j < o1; ++j) acc += Q[(size_t)srcSorted[j] * 64 + col];
    Z[(size_t)node * 64 + col] = acc;
}

// ---------------- stats: column sums/sumsq of Z (read-only) ----------------
__global__ __launch_bounds__(256) void stats_kernel(const float* __restrict__ Z,
                                                    float* __restrict__ sums,   // [64]
                                                    float* __restrict__ sumsq)  // [64]
{
    const int tid = threadIdx.x;
    const int c4 = tid & 15;
    const int rl = tid >> 4;  // 0..15
    float4 s  = {0.f, 0.f, 0.f, 0.f};
    float4 ss = {0.f, 0.f, 0.f, 0.f};
    const int rowstep = 16 * gridDim.x;
    for (int r = blockIdx.x * 16 + rl; r < NN; r += rowstep) {
        const float4 z = ((const float4*)Z)[(size_t)r * 16 + c4];
        s.x += z.x; s.y += z.y; s.z += z.z; s.w += z.w;
        ss.x += z.x * z.x; ss.y += z.y * z.y; ss.z += z.z * z.z; ss.w += z.w * z.w;
    }
    __shared__ float red[256 * 8];
    float* rp = &red[tid * 8];
    rp[0] = s.x; rp[1] = s.y; rp[2] = s.z; rp[3] = s.w;
    rp[4] = ss.x; rp[5] = ss.y; rp[6] = ss.z; rp[7] = ss.w;
    __syncthreads();
    if (tid < 16) {
        float acc[8] = {0, 0, 0, 0, 0, 0, 0, 0};
        for (int r2 = 0; r2 < 16; ++r2) {
            const float* q2 = &red[(r2 * 16 + tid) * 8];
#pragma unroll
            for (int j = 0; j < 8; ++j) acc[j] += q2[j];
        }
#pragma unroll
        for (int j = 0; j < 4; ++j) {
            atomicAdd(&sums[tid * 4 + j], acc[j]);
            atomicAdd(&sumsq[tid * 4 + j], acc[4 + j]);
        }
    }
}

// ---------------- BN finalize: scale/shift per column ----------------
__global__ void bn_finalize(const float* __restrict__ sums, const float* __restrict__ sumsq,
                            const float* __restrict__ g, const float* __restrict__ bt,
                            float* __restrict__ scale, float* __restrict__ shift)
{
    const int c = threadIdx.x;
    const float inv_n = 1.0f / (float)NN;
    const float mean = sums[c] * inv_n;
    const float var = fmaxf(sumsq[c] * inv_n - mean * mean, 0.f);
    const float sc = g[c] * rsqrtf(var + BN_EPS);
    scale[c] = sc;
    shift[c] = bt[c] - mean * sc;
}

// ---------------- gemm2: out = relu( relu(Z*scale+shift) @ W2 + b2 ); optional fused pooling ----------------
template <bool POOL>
__global__ __launch_bounds__(256) void gemm2_kernel(const float* __restrict__ Z,
                                                    const float* __restrict__ scale,
                                                    const float* __restrict__ shift,
                                                    const float* __restrict__ W2,  // [64][64]
                                                    const float* __restrict__ b2,
                                                    const int* __restrict__ batch,
                                                    float* __restrict__ out)
{
    __shared__ float sW[64 * 64];
    __shared__ float sH[16 * 64];
    const int tid = threadIdx.x;
    const int row0 = blockIdx.x * 16;

    for (int i = tid; i < 64 * 16; i += 256)
        ((float4*)sW)[i] = ((const float4*)W2)[i];
    const float4* Zb = (const float4*)(Z + (size_t)row0 * 64);
    for (int i = tid; i < 16 * 16; i += 256) {
        const float4 z = Zb[i];
        const int c4 = i & 15;
        const float4 sc = ((const float4*)scale)[c4];
        const float4 sh = ((const float4*)shift)[c4];
        float4 h;
        h.x = fmaxf(fmaf(z.x, sc.x, sh.x), 0.f);
        h.y = fmaxf(fmaf(z.y, sc.y, sh.y), 0.f);
        h.z = fmaxf(fmaf(z.z, sc.z, sh.z), 0.f);
        h.w = fmaxf(fmaf(z.w, sc.w, sh.w), 0.f);
        ((float4*)sH)[i] = h;
    }
    __syncthreads();

    const int col = tid & 63;
    const int r0  = tid >> 6;
    const float bc = b2[col];
    float acc[4] = {bc, bc, bc, bc};
    for (int k = 0; k < 64; k += 4) {
        const float w0 = sW[(k + 0) * 64 + col];
        const float w1 = sW[(k + 1) * 64 + col];
        const float w2 = sW[(k + 2) * 64 + col];
        const float w3 = sW[(k + 3) * 64 + col];
#pragma unroll
        for (int rr = 0; rr < 4; ++rr) {
            const float4 hv = *(const float4*)&sH[(r0 + rr * 4) * 64 + k];
            acc[rr] = fmaf(hv.x, w0, acc[rr]);
            acc[rr] = fmaf(hv.y, w1, acc[rr]);
            acc[rr] = fmaf(hv.z, w2, acc[rr]);
            acc[rr] = fmaf(hv.w, w3, acc[rr]);
        }
    }
#pragma unroll
    for (int rr = 0; rr < 4; ++rr) {
        const int row = row0 + r0 + rr * 4;
        const float v = fmaxf(acc[rr], 0.f);
        if (POOL) {
            atomicAdd(&out[(size_t)batch[row] * 64 + col], v);
        } else {
            out[(size_t)row * 64 + col] = v;
        }
    }
}

// ---------------- final MLP: out = relu(P @ fW1 + fb1) @ fW2 + fb2 ----------------
__global__ __launch_bounds__(256) void final_mlp(const float* __restrict__ P,   // [512][64]
                                                 const float* __restrict__ W1,  // [64][64]
                                                 const float* __restrict__ b1,
                                                 const float* __restrict__ W2,  // [64][32]
                                                 const float* __restrict__ b2,
                                                 float* __restrict__ out)       // [512][32]
{
    __shared__ float sW1[64 * 64];
    __shared__ float sW2[64 * 32];
    __shared__ float sH[4 * 64];
    const int tid = threadIdx.x;
    const int row0 = blockIdx.x * 4;

    for (int i = tid; i < 1024; i += 256) ((float4*)sW1)[i] = ((const float4*)W1)[i];
    for (int i = tid; i < 512; i += 256) ((float4*)sW2)[i] = ((const float4*)W2)[i];
    __syncthreads();

    const int col = tid & 63;
    const int r = tid >> 6;
    float acc = b1[col];
    const float* prow = P + (size_t)(row0 + r) * 64;
    for (int k = 0; k < 64; ++k) acc = fmaf(prow[k], sW1[k * 64 + col], acc);
    sH[r * 64 + col] = fmaxf(acc, 0.f);
    __syncthreads();

    if (tid < 128) {
        const int c = tid & 31;
        const int r2 = tid >> 5;
        float a2 = b2[c];
        for (int k = 0; k < 64; ++k) a2 = fmaf(sH[r2 * 64 + k], sW2[k * 32 + c], a2);
        out[(size_t)(row0 + r2) * 32 + c] = a2;
    }
}

extern "C" void kernel_launch(void* const* d_in, const int* in_sizes, int n_in,
                              void* d_out, int out_size, void* d_ws, size_t ws_size,
                              hipStream_t stream)
{
    const float* x   = (const float*)d_in[0];
    const int* ei    = (const int*)d_in[1];   // [2][E]: first E = src, next E = dst
    const int* batch = (const int*)d_in[2];
    const float* cW1[3] = {(const float*)d_in[4],  (const float*)d_in[10], (const float*)d_in[16]};
    const float* cb1[3] = {(const float*)d_in[5],  (const float*)d_in[11], (const float*)d_in[17]};
    const float* cg1[3] = {(const float*)d_in[6],  (const float*)d_in[12], (const float*)d_in[18]};
    const float* cbt[3] = {(const float*)d_in[7],  (const float*)d_in[13], (const float*)d_in[19]};
    const float* cW2[3] = {(const float*)d_in[8],  (const float*)d_in[14], (const float*)d_in[20]};
    const float* cb2[3] = {(const float*)d_in[9],  (const float*)d_in[15], (const float*)d_in[21]};
    const float* fW1 = (const float*)d_in[22];
    const float* fb1 = (const float*)d_in[23];
    const float* fW2 = (const float*)d_in[24];
    const float* fb2 = (const float*)d_in[25];
    float* out = (float*)d_out;

    // float workspace
    float* bufX   = (float*)d_ws;              // N*64; doubles as Z (gemm2 stages its rows in LDS first)
    float* q      = bufX + (size_t)NN * 64;    // N*64
    float* pooled = q + (size_t)NN * 64;       // B*64
    float* sums   = pooled + (size_t)BB * 64;  // 64
    float* sumsq  = sums + 64;
    float* scale  = sumsq + 64;
    float* shift  = scale + 64;
    // int workspace
    int* offs      = (int*)(shift + 64);       // N+1
    int* cursor    = offs + (NN + 1);          // N+1 (also used as deg histogram)
    int* blockSums = cursor + (NN + 1);        // 256
    int* blockOff  = blockSums + 256;          // 256
    int* srcSorted = blockOff + 256;           // E

    const int* esrc = ei;
    const int* edst = ei + EE;

    const int gemm_blocks = NN / 16;   // 3125
    const int edge_blocks = EE / 256;  // 3125

    // ---- build CSR by dst (once per call) ----
    hipMemsetAsync(cursor, 0, (NN + 1) * sizeof(int), stream);
    hist_kernel<<<edge_blocks, 256, 0, stream>>>(edst, cursor);
    scanA_kernel<<<SCAN_BLOCKS, 256, 0, stream>>>(cursor, offs, blockSums);
    scanB_kernel<<<1, 256, 0, stream>>>(blockSums, blockOff);
    scanC_kernel<<<SCAN_BLOCKS, 256, 0, stream>>>(offs, cursor, blockOff);
    scatter_kernel<<<edge_blocks, 256, 0, stream>>>(esrc, edst, cursor, srcSorted);

    for (int layer = 0; layer < 3; ++layer) {
        // 1) projection q = x_cur @ W1
        if (layer == 0)
            proj_kernel<DIN><<<gemm_blocks, 256, 0, stream>>>(x, cW1[0], q);
        else
            proj_kernel<HH><<<gemm_blocks, 256, 0, stream>>>(bufX, cW1[layer], q);

        // 2) gather-aggregate: Z = q + b1 + sum_{src->n} q[src]   (Z aliases bufX)
        gather_kernel<<<NN / 4, 256, 0, stream>>>(q, offs, srcSorted, cb1[layer], bufX);

        // 3) BN column stats over Z
        hipMemsetAsync(sums, 0, 128 * sizeof(float), stream);
        stats_kernel<<<200, 256, 0, stream>>>(bufX, sums, sumsq);

        // 4) BN scale/shift
        bn_finalize<<<1, 64, 0, stream>>>(sums, sumsq, cg1[layer], cbt[layer], scale, shift);

        // 5) second linear (+ReLU); last layer fuses graph pooling
        if (layer < 2) {
            gemm2_kernel<false><<<gemm_blocks, 256, 0, stream>>>(bufX, scale, shift, cW2[layer],
                                                                 cb2[layer], nullptr, bufX);
        } else {
            hipMemsetAsync(pooled, 0, (size_t)BB * 64 * sizeof(float), stream);
            gemm2_kernel<true><<<gemm_blocks, 256, 0, stream>>>(bufX, scale, shift, cW2[layer],
                                                                cb2[layer], batch, pooled);
        }
    }

    // final MLP on pooled graph features
    final_mlp<<<BB / 4, 256, 0, stream>>>(pooled, fW1, fb1, fW2, fb2, out);
}

// Round 3
// 402.763 us; speedup vs baseline: 5.5887x; 1.0130x over previous
//
#include <hip/hip_runtime.h>
#include <hip/hip_fp16.h>

#define NN 50000
#define EE 800000
#define BB 512
#define DIN 128
#define HH 64
#define DOUT 32
#define BN_EPS 1e-5f
#define SCAN_BLOCKS 196   // ceil(50000/256)
#define NGRP 6250         // 50000 / 8 nodes per group
#define GATHER_GRID 1024

// ---------------- proj: Qh = half(X @ W)  (no bias; bias folded into gather) ----------------
template <int CIN>
__global__ __launch_bounds__(256) void proj_kernel(const float* __restrict__ X,
                                                   const float* __restrict__ W,  // [CIN][64]
                                                   __half2* __restrict__ Qh)     // [N][32]
{
    __shared__ float sW[CIN * 64];
    __shared__ float sX[16 * CIN];
    const int tid = threadIdx.x;
    const int row0 = blockIdx.x * 16;

    for (int i = tid; i < CIN * 16; i += 256)
        ((float4*)sW)[i] = ((const float4*)W)[i];
    const float* Xb = X + (size_t)row0 * CIN;
    for (int i = tid; i < 16 * CIN / 4; i += 256)
        ((float4*)sX)[i] = ((const float4*)Xb)[i];
    __syncthreads();

    const int col2 = tid & 31;   // column pair
    const int rg   = tid >> 5;   // 0..7 -> rows rg*2, rg*2+1
    float2 acc0 = {0.f, 0.f};
    float2 acc1 = {0.f, 0.f};
    const float* x0p = &sX[(rg * 2 + 0) * CIN];
    const float* x1p = &sX[(rg * 2 + 1) * CIN];
#pragma unroll 4
    for (int k = 0; k < CIN; ++k) {
        const float2 w = *(const float2*)&sW[k * 64 + col2 * 2];
        const float x0 = x0p[k];
        const float x1 = x1p[k];
        acc0.x = fmaf(x0, w.x, acc0.x);
        acc0.y = fmaf(x0, w.y, acc0.y);
        acc1.x = fmaf(x1, w.x, acc1.x);
        acc1.y = fmaf(x1, w.y, acc1.y);
    }
    const int r0 = row0 + rg * 2;
    Qh[(size_t)(r0 + 0) * 32 + col2] = __floats2half2_rn(acc0.x, acc0.y);
    Qh[(size_t)(r0 + 1) * 32 + col2] = __floats2half2_rn(acc1.x, acc1.y);
}

// ---------------- CSR build ----------------
__global__ __launch_bounds__(256) void hist_rank_kernel(const int* __restrict__ dst,
                                                        int* __restrict__ deg,
                                                        int* __restrict__ rank)
{
    const int e = blockIdx.x * 256 + threadIdx.x;  // exactly E threads
    rank[e] = atomicAdd(&deg[dst[e]], 1);
}

__global__ __launch_bounds__(256) void scanA_kernel(const int* __restrict__ deg,
                                                    int* __restrict__ offs,
                                                    int* __restrict__ blockSums)
{
    __shared__ int s[256];
    const int t = threadIdx.x;
    const int i = blockIdx.x * 256 + t;
    const int v = (i < NN) ? deg[i] : 0;
    s[t] = v;
    __syncthreads();
    for (int off = 1; off < 256; off <<= 1) {
        const int a = (t >= off) ? s[t - off] : 0;
        __syncthreads();
        s[t] += a;
        __syncthreads();
    }
    if (i < NN) offs[i] = s[t] - v;  // exclusive intra-block
    if (t == 255) blockSums[blockIdx.x] = s[255];
}

__global__ __launch_bounds__(256) void scanB_kernel(const int* __restrict__ blockSums,
                                                    int* __restrict__ blockOff)
{
    __shared__ int s[256];
    const int t = threadIdx.x;
    const int v = (t < SCAN_BLOCKS) ? blockSums[t] : 0;
    s[t] = v;
    __syncthreads();
    for (int off = 1; off < 256; off <<= 1) {
        const int a = (t >= off) ? s[t - off] : 0;
        __syncthreads();
        s[t] += a;
        __syncthreads();
    }
    if (t < SCAN_BLOCKS) blockOff[t] = s[t] - v;  // exclusive
}

__global__ __launch_bounds__(256) void scanC_kernel(int* __restrict__ offs,
                                                    const int* __restrict__ blockOff,
                                                    float* __restrict__ statsbuf,  // 384 floats
                                                    float* __restrict__ pooled)    // B*64
{
    const int i = blockIdx.x * 256 + threadIdx.x;
    if (i < NN) offs[i] += blockOff[blockIdx.x];
    if (i == 0) offs[NN] = EE;
    if (i < 384) statsbuf[i] = 0.f;
    if (i < BB * 64) pooled[i] = 0.f;
}

__global__ __launch_bounds__(256) void scatter_kernel(const int* __restrict__ src,
                                                      const int* __restrict__ dst,
                                                      const int* __restrict__ rank,
                                                      const int* __restrict__ offs,
                                                      int* __restrict__ srcSorted)
{
    const int e = blockIdx.x * 256 + threadIdx.x;  // exactly E threads
    const int pos = offs[dst[e]] + rank[e];
    srcSorted[pos] = src[e];
}

// ---------------- gather: Z[n] = Q[n] + b1 + sum_{src} Q[src]; fused BN column stats ----------------
__global__ __launch_bounds__(256) void gather_kernel(const __half2* __restrict__ Qh,
                                                     const int* __restrict__ offs,
                                                     const int* __restrict__ srcSorted,
                                                     const float* __restrict__ b1,
                                                     float* __restrict__ Z,
                                                     float* __restrict__ sums,   // [64]
                                                     float* __restrict__ sumsq)  // [64]
{
    const int tid  = threadIdx.x;
    const int half = tid & 31;   // column pair within row
    const int sel8 = tid >> 5;   // 0..7: node slot within group
    const float2 bb = ((const float2*)b1)[half];
    float2 s  = {0.f, 0.f};
    float2 ss = {0.f, 0.f};

    for (int g = blockIdx.x; g < NGRP; g += GATHER_GRID) {
        const int node = g * 8 + sel8;
        const int o0 = offs[node];
        const int o1 = offs[node + 1];
        float2 acc = __half22float2(Qh[(size_t)node * 32 + half]);
        acc.x += bb.x;
        acc.y += bb.y;
        int j = o0;
        for (; j + 4 <= o1; j += 4) {
            const int i0 = srcSorted[j + 0];
            const int i1 = srcSorted[j + 1];
            const int i2 = srcSorted[j + 2];
            const int i3 = srcSorted[j + 3];
            const float2 a0 = __half22float2(Qh[(size_t)i0 * 32 + half]);
            const float2 a1 = __half22float2(Qh[(size_t)i1 * 32 + half]);
            const float2 a2 = __half22float2(Qh[(size_t)i2 * 32 + half]);
            const float2 a3 = __half22float2(Qh[(size_t)i3 * 32 + half]);
            acc.x += a0.x + a1.x + a2.x + a3.x;
            acc.y += a0.y + a1.y + a2.y + a3.y;
        }
        for (; j < o1; ++j) {
            const float2 a = __half22float2(Qh[(size_t)srcSorted[j] * 32 + half]);
            acc.x += a.x;
            acc.y += a.y;
        }
        ((float2*)Z)[(size_t)node * 32 + half] = acc;
        s.x += acc.x; s.y += acc.y;
        ss.x += acc.x * acc.x; ss.y += acc.y * acc.y;
    }

    // block reduce of column stats -> global atomics (1024 per address)
    __shared__ float red[8][32][4];
    red[sel8][half][0] = s.x;
    red[sel8][half][1] = s.y;
    red[sel8][half][2] = ss.x;
    red[sel8][half][3] = ss.y;
    __syncthreads();
    if (tid < 32) {
        float a0 = 0.f, a1 = 0.f, a2 = 0.f, a3 = 0.f;
#pragma unroll
        for (int r = 0; r < 8; ++r) {
            a0 += red[r][tid][0];
            a1 += red[r][tid][1];
            a2 += red[r][tid][2];
            a3 += red[r][tid][3];
        }
        atomicAdd(&sums[2 * tid + 0], a0);
        atomicAdd(&sums[2 * tid + 1], a1);
        atomicAdd(&sumsq[2 * tid + 0], a2);
        atomicAdd(&sumsq[2 * tid + 1], a3);
    }
}

// ---------------- gemm2: out = relu( relu(BN(Z)) @ W2 + b2 ); BN finalize in prologue ----------------
template <bool POOL>
__global__ __launch_bounds__(256) void gemm2_kernel(const float* __restrict__ Z,
                                                    const float* __restrict__ sums,
                                                    const float* __restrict__ sumsq,
                                                    const float* __restrict__ g1,
                                                    const float* __restrict__ bt1,
                                                    const float* __restrict__ W2,  // [64][64]
                                                    const float* __restrict__ b2,
                                                    const int* __restrict__ batch,
                                                    float* __restrict__ out)
{
    __shared__ float sW[64 * 64];
    __shared__ float sH[16 * 64];
    __shared__ float sScale[64];
    __shared__ float sShift[64];
    const int tid = threadIdx.x;
    const int row0 = blockIdx.x * 16;

    if (tid < 64) {
        const float inv_n = 1.0f / (float)NN;
        const float mean = sums[tid] * inv_n;
        const float var = fmaxf(sumsq[tid] * inv_n - mean * mean, 0.f);
        const float sc = g1[tid] * rsqrtf(var + BN_EPS);
        sScale[tid] = sc;
        sShift[tid] = bt1[tid] - mean * sc;
    }
    for (int i = tid; i < 64 * 16; i += 256)
        ((float4*)sW)[i] = ((const float4*)W2)[i];
    __syncthreads();

    const float4* Zb = (const float4*)(Z + (size_t)row0 * 64);
    {
        const int i = tid;  // 256 float4s = 16 rows x 16
        const float4 z = Zb[i];
        const int c4 = i & 15;
        const float4 sc = ((const float4*)sScale)[c4];
        const float4 sh = ((const float4*)sShift)[c4];
        float4 h;
        h.x = fmaxf(fmaf(z.x, sc.x, sh.x), 0.f);
        h.y = fmaxf(fmaf(z.y, sc.y, sh.y), 0.f);
        h.z = fmaxf(fmaf(z.z, sc.z, sh.z), 0.f);
        h.w = fmaxf(fmaf(z.w, sc.w, sh.w), 0.f);
        ((float4*)sH)[i] = h;
    }
    __syncthreads();

    const int col = tid & 63;
    const int r0  = tid >> 6;
    const float bc = b2[col];
    float acc[4] = {bc, bc, bc, bc};
    for (int k = 0; k < 64; k += 4) {
        const float w0 = sW[(k + 0) * 64 + col];
        const float w1 = sW[(k + 1) * 64 + col];
        const float w2 = sW[(k + 2) * 64 + col];
        const float w3 = sW[(k + 3) * 64 + col];
#pragma unroll
        for (int rr = 0; rr < 4; ++rr) {
            const float4 hv = *(const float4*)&sH[(r0 + rr * 4) * 64 + k];
            acc[rr] = fmaf(hv.x, w0, acc[rr]);
            acc[rr] = fmaf(hv.y, w1, acc[rr]);
            acc[rr] = fmaf(hv.z, w2, acc[rr]);
            acc[rr] = fmaf(hv.w, w3, acc[rr]);
        }
    }
#pragma unroll
    for (int rr = 0; rr < 4; ++rr) {
        const int row = row0 + r0 + rr * 4;
        const float v = fmaxf(acc[rr], 0.f);
        if (POOL) {
            atomicAdd(&out[(size_t)batch[row] * 64 + col], v);
        } else {
            out[(size_t)row * 64 + col] = v;
        }
    }
}

// ---------------- final MLP: out = relu(P @ fW1 + fb1) @ fW2 + fb2 ----------------
__global__ __launch_bounds__(256) void final_mlp(const float* __restrict__ P,   // [512][64]
                                                 const float* __restrict__ W1,  // [64][64]
                                                 const float* __restrict__ b1,
                                                 const float* __restrict__ W2,  // [64][32]
                                                 const float* __restrict__ b2,
                                                 float* __restrict__ out)       // [512][32]
{
    __shared__ float sW1[64 * 64];
    __shared__ float sW2[64 * 32];
    __shared__ float sH[4 * 64];
    const int tid = threadIdx.x;
    const int row0 = blockIdx.x * 4;

    for (int i = tid; i < 1024; i += 256) ((float4*)sW1)[i] = ((const float4*)W1)[i];
    for (int i = tid; i < 512; i += 256) ((float4*)sW2)[i] = ((const float4*)W2)[i];
    __syncthreads();

    const int col = tid & 63;
    const int r = tid >> 6;
    float acc = b1[col];
    const float* prow = P + (size_t)(row0 + r) * 64;
    for (int k = 0; k < 64; ++k) acc = fmaf(prow[k], sW1[k * 64 + col], acc);
    sH[r * 64 + col] = fmaxf(acc, 0.f);
    __syncthreads();

    if (tid < 128) {
        const int c = tid & 31;
        const int r2 = tid >> 5;
        float a2 = b2[c];
        for (int k = 0; k < 64; ++k) a2 = fmaf(sH[r2 * 64 + k], sW2[k * 32 + c], a2);
        out[(size_t)(row0 + r2) * 32 + c] = a2;
    }
}

extern "C" void kernel_launch(void* const* d_in, const int* in_sizes, int n_in,
                              void* d_out, int out_size, void* d_ws, size_t ws_size,
                              hipStream_t stream)
{
    const float* x   = (const float*)d_in[0];
    const int* ei    = (const int*)d_in[1];   // [2][E]: first E = src, next E = dst
    const int* batch = (const int*)d_in[2];
    const float* cW1[3] = {(const float*)d_in[4],  (const float*)d_in[10], (const float*)d_in[16]};
    const float* cb1[3] = {(const float*)d_in[5],  (const float*)d_in[11], (const float*)d_in[17]};
    const float* cg1[3] = {(const float*)d_in[6],  (const float*)d_in[12], (const float*)d_in[18]};
    const float* cbt[3] = {(const float*)d_in[7],  (const float*)d_in[13], (const float*)d_in[19]};
    const float* cW2[3] = {(const float*)d_in[8],  (const float*)d_in[14], (const float*)d_in[20]};
    const float* cb2[3] = {(const float*)d_in[9],  (const float*)d_in[15], (const float*)d_in[21]};
    const float* fW1 = (const float*)d_in[22];
    const float* fb1 = (const float*)d_in[23];
    const float* fW2 = (const float*)d_in[24];
    const float* fb2 = (const float*)d_in[25];
    float* out = (float*)d_out;

    // workspace layout
    float* bufX     = (float*)d_ws;                   // N*64 fp32: X for layers>=1, Z (in-place safe)
    __half2* Qh     = (__half2*)(bufX + (size_t)NN * 64);  // N*32 half2
    float* pooled   = (float*)(Qh + (size_t)NN * 32); // B*64
    float* statsbuf = pooled + (size_t)BB * 64;       // 3 layers x (64 sums + 64 sumsq)
    int* deg        = (int*)(statsbuf + 384);         // N
    int* offs       = deg + NN;                       // N+1
    int* rank       = offs + (NN + 1);                // E
    int* blockSums  = rank + EE;                      // 256
    int* blockOff   = blockSums + 256;                // 256
    int* srcSorted  = blockOff + 256;                 // E

    const int* esrc = ei;
    const int* edst = ei + EE;

    const int gemm_blocks = NN / 16;   // 3125
    const int edge_blocks = EE / 256;  // 3125

    // ---- build CSR by dst ----
    hipMemsetAsync(deg, 0, NN * sizeof(int), stream);
    hist_rank_kernel<<<edge_blocks, 256, 0, stream>>>(edst, deg, rank);
    scanA_kernel<<<SCAN_BLOCKS, 256, 0, stream>>>(deg, offs, blockSums);
    scanB_kernel<<<1, 256, 0, stream>>>(blockSums, blockOff);
    scanC_kernel<<<SCAN_BLOCKS, 256, 0, stream>>>(offs, blockOff, statsbuf, pooled);
    scatter_kernel<<<edge_blocks, 256, 0, stream>>>(esrc, edst, rank, offs, srcSorted);

    for (int layer = 0; layer < 3; ++layer) {
        float* sums  = statsbuf + layer * 128;
        float* sumsq = sums + 64;

        // 1) projection Qh = half(x_cur @ W1)
        if (layer == 0)
            proj_kernel<DIN><<<gemm_blocks, 256, 0, stream>>>(x, cW1[0], Qh);
        else
            proj_kernel<HH><<<gemm_blocks, 256, 0, stream>>>(bufX, cW1[layer], Qh);

        // 2) gather-aggregate + fused BN stats (Z aliases bufX; gemm2 is row-local in-place)
        gather_kernel<<<GATHER_GRID, 256, 0, stream>>>(Qh, offs, srcSorted, cb1[layer],
                                                       bufX, sums, sumsq);

        // 3) BN finalize (in gemm2 prologue) + second linear + ReLU; last layer fuses pooling
        if (layer < 2) {
            gemm2_kernel<false><<<gemm_blocks, 256, 0, stream>>>(bufX, sums, sumsq, cg1[layer],
                                                                 cbt[layer], cW2[layer], cb2[layer],
                                                                 nullptr, bufX);
        } else {
            gemm2_kernel<true><<<gemm_blocks, 256, 0, stream>>>(bufX, sums, sumsq, cg1[layer],
                                                                cbt[layer], cW2[layer], cb2[layer],
                                                                batch, pooled);
        }
    }

    // final MLP on pooled graph features
    final_mlp<<<BB / 4, 256, 0, stream>>>(pooled, fW1, fb1, fW2, fb2, out);
}

// Round 4
// 341.847 us; speedup vs baseline: 6.5846x; 1.1782x over previous
//
#include <hip/hip_runtime.h>
#include <hip/hip_fp16.h>

#define NN 50000
#define EE 800000
#define BB 512
#define DIN 128
#define HH 64
#define DOUT 32
#define BN_EPS 1e-5f
#define SCAN_BLOCKS 196   // ceil(50000/256)
#define GATHER_BLOCKS 1024

// ---------------- proj: Qh = half(X @ W)  (no bias; bias folded into gather) ----------------
template <int CIN>
__global__ __launch_bounds__(256) void proj_kernel(const float* __restrict__ X,
                                                   const float* __restrict__ W,  // [CIN][64]
                                                   __half2* __restrict__ Qh)     // [N][32]
{
    __shared__ float sW[CIN * 64];
    __shared__ float sX[16 * CIN];
    const int tid = threadIdx.x;
    const int row0 = blockIdx.x * 16;

    for (int i = tid; i < CIN * 16; i += 256)
        ((float4*)sW)[i] = ((const float4*)W)[i];
    const float* Xb = X + (size_t)row0 * CIN;
    for (int i = tid; i < 16 * CIN / 4; i += 256)
        ((float4*)sX)[i] = ((const float4*)Xb)[i];
    __syncthreads();

    const int col2 = tid & 31;   // column pair
    const int rg   = tid >> 5;   // 0..7 -> rows rg*2, rg*2+1
    float2 acc0 = {0.f, 0.f};
    float2 acc1 = {0.f, 0.f};
    const float* x0p = &sX[(rg * 2 + 0) * CIN];
    const float* x1p = &sX[(rg * 2 + 1) * CIN];
#pragma unroll 4
    for (int k = 0; k < CIN; ++k) {
        const float2 w = *(const float2*)&sW[k * 64 + col2 * 2];
        const float x0 = x0p[k];
        const float x1 = x1p[k];
        acc0.x = fmaf(x0, w.x, acc0.x);
        acc0.y = fmaf(x0, w.y, acc0.y);
        acc1.x = fmaf(x1, w.x, acc1.x);
        acc1.y = fmaf(x1, w.y, acc1.y);
    }
    const int r0 = row0 + rg * 2;
    Qh[(size_t)(r0 + 0) * 32 + col2] = __floats2half2_rn(acc0.x, acc0.y);
    Qh[(size_t)(r0 + 1) * 32 + col2] = __floats2half2_rn(acc1.x, acc1.y);
}

// ---------------- CSR build ----------------
__global__ __launch_bounds__(256) void hist_rank_kernel(const int* __restrict__ dst,
                                                        int* __restrict__ deg,
                                                        unsigned short* __restrict__ rank)
{
    const int e = blockIdx.x * 256 + threadIdx.x;  // exactly E threads
    rank[e] = (unsigned short)atomicAdd(&deg[dst[e]], 1);
}

__global__ __launch_bounds__(256) void scanA_kernel(const int* __restrict__ deg,
                                                    int* __restrict__ offs,
                                                    int* __restrict__ blockSums)
{
    __shared__ int s[256];
    const int t = threadIdx.x;
    const int i = blockIdx.x * 256 + t;
    const int v = (i < NN) ? deg[i] : 0;
    s[t] = v;
    __syncthreads();
    for (int off = 1; off < 256; off <<= 1) {
        const int a = (t >= off) ? s[t - off] : 0;
        __syncthreads();
        s[t] += a;
        __syncthreads();
    }
    if (i < NN) offs[i] = s[t] - v;  // exclusive intra-block
    if (t == 255) blockSums[blockIdx.x] = s[255];
}

__global__ __launch_bounds__(256) void scanB_kernel(const int* __restrict__ blockSums,
                                                    int* __restrict__ blockOff)
{
    __shared__ int s[256];
    const int t = threadIdx.x;
    const int v = (t < SCAN_BLOCKS) ? blockSums[t] : 0;
    s[t] = v;
    __syncthreads();
    for (int off = 1; off < 256; off <<= 1) {
        const int a = (t >= off) ? s[t - off] : 0;
        __syncthreads();
        s[t] += a;
        __syncthreads();
    }
    if (t < SCAN_BLOCKS) blockOff[t] = s[t] - v;  // exclusive
}

__global__ __launch_bounds__(256) void scanC_kernel(int* __restrict__ offs,
                                                    const int* __restrict__ blockOff,
                                                    float* __restrict__ statsbuf,  // 384 floats
                                                    float* __restrict__ pooled)    // B*64
{
    const int i = blockIdx.x * 256 + threadIdx.x;
    if (i < NN) offs[i] += blockOff[blockIdx.x];
    if (i == 0) offs[NN] = EE;
    if (i < 384) statsbuf[i] = 0.f;
    if (i < BB * 64) pooled[i] = 0.f;
}

__global__ __launch_bounds__(256) void scatter_kernel(const int* __restrict__ src,
                                                      const int* __restrict__ dst,
                                                      const unsigned short* __restrict__ rank,
                                                      const int* __restrict__ offs,
                                                      unsigned short* __restrict__ srcSorted)
{
    const int e = blockIdx.x * 256 + threadIdx.x;  // exactly E threads
    const int pos = offs[dst[e]] + (int)rank[e];
    srcSorted[pos] = (unsigned short)src[e];
}

// ---------------- gather: Z[n] = Q[n] + b1 + sum_{src} Q[src]; fused BN column stats ----------------
// One wave per node; 16 lanes per row (8B/lane), 4 edges per load instruction, 16-deep pipeline.
__global__ __launch_bounds__(256) void gather_kernel(const __half2* __restrict__ Qh,
                                                     const int* __restrict__ offs,
                                                     const unsigned short* __restrict__ srcSorted,
                                                     const float* __restrict__ b1,
                                                     float* __restrict__ Z,
                                                     float* __restrict__ sums,   // [64]
                                                     float* __restrict__ sumsq)  // [64]
{
    const int tid  = threadIdx.x;
    const int lane = tid & 63;
    const int wid  = tid >> 6;        // wave in block: 0..3
    const int colq = lane & 15;       // column quad (4 halfs = 8B)
    const int grp  = lane >> 4;       // 0..3: edge slot
    const uint2* Qr = (const uint2*)Qh;   // 16 uint2 per row
    const float4 bb = ((const float4*)b1)[colq];

    float sa0 = 0.f, sa1 = 0.f, sa2 = 0.f, sa3 = 0.f;
    float ta0 = 0.f, ta1 = 0.f, ta2 = 0.f, ta3 = 0.f;

    for (int node = blockIdx.x * 4 + wid; node < NN; node += GATHER_BLOCKS * 4) {
        const int o0 = offs[node];
        const int o1 = offs[node + 1];
        float a0 = 0.f, a1 = 0.f, a2 = 0.f, a3 = 0.f;
        int j = o0;
        for (; j + 16 <= o1; j += 16) {
            const int e0 = srcSorted[j + grp];
            const int e1 = srcSorted[j + 4 + grp];
            const int e2 = srcSorted[j + 8 + grp];
            const int e3 = srcSorted[j + 12 + grp];
            const uint2 r0 = Qr[(size_t)e0 * 16 + colq];
            const uint2 r1 = Qr[(size_t)e1 * 16 + colq];
            const uint2 r2 = Qr[(size_t)e2 * 16 + colq];
            const uint2 r3 = Qr[(size_t)e3 * 16 + colq];
            float2 p;
            p = __half22float2(*(const __half2*)&r0.x); a0 += p.x; a1 += p.y;
            p = __half22float2(*(const __half2*)&r0.y); a2 += p.x; a3 += p.y;
            p = __half22float2(*(const __half2*)&r1.x); a0 += p.x; a1 += p.y;
            p = __half22float2(*(const __half2*)&r1.y); a2 += p.x; a3 += p.y;
            p = __half22float2(*(const __half2*)&r2.x); a0 += p.x; a1 += p.y;
            p = __half22float2(*(const __half2*)&r2.y); a2 += p.x; a3 += p.y;
            p = __half22float2(*(const __half2*)&r3.x); a0 += p.x; a1 += p.y;
            p = __half22float2(*(const __half2*)&r3.y); a2 += p.x; a3 += p.y;
        }
        for (; j + 4 <= o1; j += 4) {
            const int e0 = srcSorted[j + grp];
            const uint2 r0 = Qr[(size_t)e0 * 16 + colq];
            float2 p;
            p = __half22float2(*(const __half2*)&r0.x); a0 += p.x; a1 += p.y;
            p = __half22float2(*(const __half2*)&r0.y); a2 += p.x; a3 += p.y;
        }
        if (grp < o1 - j) {
            const int e0 = srcSorted[j + grp];
            const uint2 r0 = Qr[(size_t)e0 * 16 + colq];
            float2 p;
            p = __half22float2(*(const __half2*)&r0.x); a0 += p.x; a1 += p.y;
            p = __half22float2(*(const __half2*)&r0.y); a2 += p.x; a3 += p.y;
        }
        // combine the 4 edge-groups: all lanes end with the full column sums
        a0 += __shfl_xor(a0, 16); a1 += __shfl_xor(a1, 16);
        a2 += __shfl_xor(a2, 16); a3 += __shfl_xor(a3, 16);
        a0 += __shfl_xor(a0, 32); a1 += __shfl_xor(a1, 32);
        a2 += __shfl_xor(a2, 32); a3 += __shfl_xor(a3, 32);
        if (grp == 0) {
            const uint2 sr = Qr[(size_t)node * 16 + colq];
            float2 p;
            p = __half22float2(*(const __half2*)&sr.x); a0 += p.x + bb.x; a1 += p.y + bb.y;
            p = __half22float2(*(const __half2*)&sr.y); a2 += p.x + bb.z; a3 += p.y + bb.w;
            float4 zv = {a0, a1, a2, a3};
            ((float4*)Z)[(size_t)node * 16 + colq] = zv;
            sa0 += a0; sa1 += a1; sa2 += a2; sa3 += a3;
            ta0 += a0 * a0; ta1 += a1 * a1; ta2 += a2 * a2; ta3 += a3 * a3;
        }
    }

    // block-level stats reduce: 4 waves x 16 colq x 8 values -> 128 atomics
    __shared__ float red[4][16][8];
    if (grp == 0) {
        float* rp = red[wid][colq];
        rp[0] = sa0; rp[1] = sa1; rp[2] = sa2; rp[3] = sa3;
        rp[4] = ta0; rp[5] = ta1; rp[6] = ta2; rp[7] = ta3;
    }
    __syncthreads();
    if (tid < 128) {
        const int cq = tid >> 3;
        const int k  = tid & 7;
        const float v = red[0][cq][k] + red[1][cq][k] + red[2][cq][k] + red[3][cq][k];
        float* dstp = (k < 4) ? &sums[cq * 4 + k] : &sumsq[cq * 4 + (k - 4)];
        atomicAdd(dstp, v);
    }
}

// ---------------- gemm2: out = relu( relu(BN(Z)) @ W2 + b2 ); BN finalize in prologue ----------------
template <bool POOL>
__global__ __launch_bounds__(256) void gemm2_kernel(const float* __restrict__ Z,
                                                    const float* __restrict__ sums,
                                                    const float* __restrict__ sumsq,
                                                    const float* __restrict__ g1,
                                                    const float* __restrict__ bt1,
                                                    const float* __restrict__ W2,  // [64][64]
                                                    const float* __restrict__ b2,
                                                    const int* __restrict__ batch,
                                                    float* __restrict__ out)
{
    __shared__ float sW[64 * 64];
    __shared__ float sH[16 * 64];
    __shared__ float sScale[64];
    __shared__ float sShift[64];
    const int tid = threadIdx.x;
    const int row0 = blockIdx.x * 16;

    if (tid < 64) {
        const float inv_n = 1.0f / (float)NN;
        const float mean = sums[tid] * inv_n;
        const float var = fmaxf(sumsq[tid] * inv_n - mean * mean, 0.f);
        const float sc = g1[tid] * rsqrtf(var + BN_EPS);
        sScale[tid] = sc;
        sShift[tid] = bt1[tid] - mean * sc;
    }
    for (int i = tid; i < 64 * 16; i += 256)
        ((float4*)sW)[i] = ((const float4*)W2)[i];
    __syncthreads();

    const float4* Zb = (const float4*)(Z + (size_t)row0 * 64);
    {
        const int i = tid;  // 256 float4s = 16 rows x 16
        const float4 z = Zb[i];
        const int c4 = i & 15;
        const float4 sc = ((const float4*)sScale)[c4];
        const float4 sh = ((const float4*)sShift)[c4];
        float4 h;
        h.x = fmaxf(fmaf(z.x, sc.x, sh.x), 0.f);
        h.y = fmaxf(fmaf(z.y, sc.y, sh.y), 0.f);
        h.z = fmaxf(fmaf(z.z, sc.z, sh.z), 0.f);
        h.w = fmaxf(fmaf(z.w, sc.w, sh.w), 0.f);
        ((float4*)sH)[i] = h;
    }
    __syncthreads();

    const int col = tid & 63;
    const int r0  = tid >> 6;
    const float bc = b2[col];
    float acc[4] = {bc, bc, bc, bc};
    for (int k = 0; k < 64; k += 4) {
        const float w0 = sW[(k + 0) * 64 + col];
        const float w1 = sW[(k + 1) * 64 + col];
        const float w2 = sW[(k + 2) * 64 + col];
        const float w3 = sW[(k + 3) * 64 + col];
#pragma unroll
        for (int rr = 0; rr < 4; ++rr) {
            const float4 hv = *(const float4*)&sH[(r0 + rr * 4) * 64 + k];
            acc[rr] = fmaf(hv.x, w0, acc[rr]);
            acc[rr] = fmaf(hv.y, w1, acc[rr]);
            acc[rr] = fmaf(hv.z, w2, acc[rr]);
            acc[rr] = fmaf(hv.w, w3, acc[rr]);
        }
    }
#pragma unroll
    for (int rr = 0; rr < 4; ++rr) {
        const int row = row0 + r0 + rr * 4;
        const float v = fmaxf(acc[rr], 0.f);
        if (POOL) {
            atomicAdd(&out[(size_t)batch[row] * 64 + col], v);
        } else {
            out[(size_t)row * 64 + col] = v;
        }
    }
}

// ---------------- final MLP: out = relu(P @ fW1 + fb1) @ fW2 + fb2 ----------------
__global__ __launch_bounds__(256) void final_mlp(const float* __restrict__ P,   // [512][64]
                                                 const float* __restrict__ W1,  // [64][64]
                                                 const float* __restrict__ b1,
                                                 const float* __restrict__ W2,  // [64][32]
                                                 const float* __restrict__ b2,
                                                 float* __restrict__ out)       // [512][32]
{
    __shared__ float sW1[64 * 64];
    __shared__ float sW2[64 * 32];
    __shared__ float sH[4 * 64];
    const int tid = threadIdx.x;
    const int row0 = blockIdx.x * 4;

    for (int i = tid; i < 1024; i += 256) ((float4*)sW1)[i] = ((const float4*)W1)[i];
    for (int i = tid; i < 512; i += 256) ((float4*)sW2)[i] = ((const float4*)W2)[i];
    __syncthreads();

    const int col = tid & 63;
    const int r = tid >> 6;
    float acc = b1[col];
    const float* prow = P + (size_t)(row0 + r) * 64;
    for (int k = 0; k < 64; ++k) acc = fmaf(prow[k], sW1[k * 64 + col], acc);
    sH[r * 64 + col] = fmaxf(acc, 0.f);
    __syncthreads();

    if (tid < 128) {
        const int c = tid & 31;
        const int r2 = tid >> 5;
        float a2 = b2[c];
        for (int k = 0; k < 64; ++k) a2 = fmaf(sH[r2 * 64 + k], sW2[k * 32 + c], a2);
        out[(size_t)(row0 + r2) * 32 + c] = a2;
    }
}

extern "C" void kernel_launch(void* const* d_in, const int* in_sizes, int n_in,
                              void* d_out, int out_size, void* d_ws, size_t ws_size,
                              hipStream_t stream)
{
    const float* x   = (const float*)d_in[0];
    const int* ei    = (const int*)d_in[1];   // [2][E]: first E = src, next E = dst
    const int* batch = (const int*)d_in[2];
    const float* cW1[3] = {(const float*)d_in[4],  (const float*)d_in[10], (const float*)d_in[16]};
    const float* cb1[3] = {(const float*)d_in[5],  (const float*)d_in[11], (const float*)d_in[17]};
    const float* cg1[3] = {(const float*)d_in[6],  (const float*)d_in[12], (const float*)d_in[18]};
    const float* cbt[3] = {(const float*)d_in[7],  (const float*)d_in[13], (const float*)d_in[19]};
    const float* cW2[3] = {(const float*)d_in[8],  (const float*)d_in[14], (const float*)d_in[20]};
    const float* cb2[3] = {(const float*)d_in[9],  (const float*)d_in[15], (const float*)d_in[21]};
    const float* fW1 = (const float*)d_in[22];
    const float* fb1 = (const float*)d_in[23];
    const float* fW2 = (const float*)d_in[24];
    const float* fb2 = (const float*)d_in[25];
    float* out = (float*)d_out;

    // workspace layout
    float* bufX     = (float*)d_ws;                        // N*64 fp32: X for layers>=1, Z (in-place safe)
    __half2* Qh     = (__half2*)(bufX + (size_t)NN * 64);  // N*32 half2
    float* pooled   = (float*)(Qh + (size_t)NN * 32);      // B*64
    float* statsbuf = pooled + (size_t)BB * 64;            // 3 layers x (64 sums + 64 sumsq)
    int* deg        = (int*)(statsbuf + 384);              // N
    int* offs       = deg + NN;                            // N+1
    int* blockSums  = offs + (NN + 1);                     // 256
    int* blockOff   = blockSums + 256;                     // 256
    unsigned short* rank      = (unsigned short*)(blockOff + 256);  // E
    unsigned short* srcSorted = rank + EE;                          // E

    const int* esrc = ei;
    const int* edst = ei + EE;

    const int gemm_blocks = NN / 16;   // 3125
    const int edge_blocks = EE / 256;  // 3125

    // ---- build CSR by dst ----
    hipMemsetAsync(deg, 0, NN * sizeof(int), stream);
    hist_rank_kernel<<<edge_blocks, 256, 0, stream>>>(edst, deg, rank);
    scanA_kernel<<<SCAN_BLOCKS, 256, 0, stream>>>(deg, offs, blockSums);
    scanB_kernel<<<1, 256, 0, stream>>>(blockSums, blockOff);
    scanC_kernel<<<SCAN_BLOCKS, 256, 0, stream>>>(offs, blockOff, statsbuf, pooled);
    scatter_kernel<<<edge_blocks, 256, 0, stream>>>(esrc, edst, rank, offs, srcSorted);

    for (int layer = 0; layer < 3; ++layer) {
        float* sums  = statsbuf + layer * 128;
        float* sumsq = sums + 64;

        // 1) projection Qh = half(x_cur @ W1)
        if (layer == 0)
            proj_kernel<DIN><<<gemm_blocks, 256, 0, stream>>>(x, cW1[0], Qh);
        else
            proj_kernel<HH><<<gemm_blocks, 256, 0, stream>>>(bufX, cW1[layer], Qh);

        // 2) gather-aggregate + fused BN stats (Z aliases bufX; gemm2 is row-local in-place)
        gather_kernel<<<GATHER_BLOCKS, 256, 0, stream>>>(Qh, offs, srcSorted, cb1[layer],
                                                         bufX, sums, sumsq);

        // 3) BN finalize (in gemm2 prologue) + second linear + ReLU; last layer fuses pooling
        if (layer < 2) {
            gemm2_kernel<false><<<gemm_blocks, 256, 0, stream>>>(bufX, sums, sumsq, cg1[layer],
                                                                 cbt[layer], cW2[layer], cb2[layer],
                                                                 nullptr, bufX);
        } else {
            gemm2_kernel<true><<<gemm_blocks, 256, 0, stream>>>(bufX, sums, sumsq, cg1[layer],
                                                                cbt[layer], cW2[layer], cb2[layer],
                                                                batch, pooled);
        }
    }

    // final MLP on pooled graph features
    final_mlp<<<BB / 4, 256, 0, stream>>>(pooled, fW1, fb1, fW2, fb2, out);
}